// Round 1
// baseline (501.583 us; speedup 1.0000x reference)
//
#include <hip/hip_runtime.h>
#include <hip/hip_bf16.h>

// SelfAttention: B=4, S=2048, D=1024, fp32 in/out.
// Round 1: correctness-first bf16-MFMA decomposition:
//   1) cast x -> bf16; cast+transpose Wq/Wk/Wv -> bf16 [N,K]
//   2) gemm_nt: q,k,v = x @ W^T   (M=8192, N=1024, K=1024), bf16 out
//   3) transpose v -> vt [B][D][S]
//   4) per batch: scores = q k^T / 32 (fp32), row softmax -> bf16 w,
//                 out = w @ vt^T (fp32)
// gemm_nt is the m97-style structure: 128x128 tile, BK=32,
// global_load_lds width=16 staging, 16x16x32 bf16 MFMA, 4 waves x 4x4 subtiles.
// Workspace use: ~110 MB.

typedef __bf16 bf16_t;
typedef __bf16 bf16x8 __attribute__((ext_vector_type(8)));
typedef __bf16 bf16x4v __attribute__((ext_vector_type(4)));
typedef float f32x4 __attribute__((ext_vector_type(4)));

__device__ __forceinline__ void load16_to_lds(const bf16_t* g, bf16_t* l) {
  __builtin_amdgcn_global_load_lds(
      (const __attribute__((address_space(1))) void*)g,
      (__attribute__((address_space(3))) void*)l,
      16, 0, 0);
}

// C[M,N] = scale * (A[M,K] @ B[N,K]^T); A,B bf16 K-major, C row-major OutT.
template <typename OutT>
__global__ __launch_bounds__(256) void gemm_nt(
    const bf16_t* __restrict__ A, const bf16_t* __restrict__ Bm,
    OutT* __restrict__ C, int M, int N, int K, float scale) {
  __shared__ __align__(16) bf16_t As[128 * 32];
  __shared__ __align__(16) bf16_t Bs[128 * 32];

  const int t    = threadIdx.x;
  const int m0   = blockIdx.y * 128;
  const int n0   = blockIdx.x * 128;
  const int wave = t >> 6;
  const int lane = t & 63;
  const int wm   = (wave >> 1) * 64;   // wave row offset in tile
  const int wn   = (wave & 1) * 64;    // wave col offset in tile
  const int lm   = lane & 15;          // m/n index within 16x16 subtile
  const int lq   = lane >> 4;          // quad: k-group (inputs), row-group (output)

  // Staging: A tile is 128 rows x 32 k (64B/row = 4 x 16B chunks).
  // 512 chunks over 256 threads -> 2 chunks per thread per matrix.
  // Chunk c -> LDS offset c*16B (unpadded row-major, matches the
  // wave-uniform-base + lane*16 semantics of global_load_lds).
  const int srow = t >> 2;         // 0..63
  const int scc  = (t & 3) * 8;    // k offset in elements: 0,8,16,24

  const bf16_t* gA0 = A  + (size_t)(m0 + srow) * K + scc;
  const bf16_t* gA1 = gA0 + (size_t)64 * K;
  const bf16_t* gB0 = Bm + (size_t)(n0 + srow) * K + scc;
  const bf16_t* gB1 = gB0 + (size_t)64 * K;

  bf16_t* lA0 = &As[t * 8];
  bf16_t* lA1 = &As[(256 + t) * 8];
  bf16_t* lB0 = &Bs[t * 8];
  bf16_t* lB1 = &Bs[(256 + t) * 8];

  f32x4 acc[4][4] = {};

  for (int k0 = 0; k0 < K; k0 += 32) {
    __syncthreads();  // previous iter's LDS reads complete
    load16_to_lds(gA0 + k0, lA0);
    load16_to_lds(gA1 + k0, lA1);
    load16_to_lds(gB0 + k0, lB0);
    load16_to_lds(gB1 + k0, lB1);
    __syncthreads();  // staging drained (compiler emits vmcnt(0) before barrier)

    bf16x8 a[4], b[4];
#pragma unroll
    for (int i = 0; i < 4; ++i)
      a[i] = *(const bf16x8*)&As[(wm + i * 16 + lm) * 32 + lq * 8];
#pragma unroll
    for (int j = 0; j < 4; ++j)
      b[j] = *(const bf16x8*)&Bs[(wn + j * 16 + lm) * 32 + lq * 8];
#pragma unroll
    for (int i = 0; i < 4; ++i)
#pragma unroll
      for (int j = 0; j < 4; ++j)
        acc[i][j] = __builtin_amdgcn_mfma_f32_16x16x32_bf16(a[i], b[j], acc[i][j], 0, 0, 0);
  }

  // Epilogue: C/D layout col = lane&15, row = (lane>>4)*4 + reg  [m89-verified]
#pragma unroll
  for (int i = 0; i < 4; ++i) {
#pragma unroll
    for (int j = 0; j < 4; ++j) {
      const int col = n0 + wn + j * 16 + lm;
#pragma unroll
      for (int r = 0; r < 4; ++r) {
        const int row = m0 + wm + i * 16 + lq * 4 + r;
        C[(size_t)row * N + col] = (OutT)(acc[i][j][r] * scale);
      }
    }
  }
}

__global__ __launch_bounds__(256) void cast_f32_to_bf16(
    const float* __restrict__ in, bf16_t* __restrict__ out, int n) {
  int i = (blockIdx.x * 256 + threadIdx.x) * 4;
  if (i >= n) return;
  const float4 v = *reinterpret_cast<const float4*>(in + i);
  bf16x4v o;
  o.x = (__bf16)v.x; o.y = (__bf16)v.y; o.z = (__bf16)v.z; o.w = (__bf16)v.w;
  *reinterpret_cast<bf16x4v*>(out + i) = o;
}

// out[c][r] = (bf16)in[r][c], in fp32 [rows][cols]
__global__ __launch_bounds__(256) void cast_transpose(
    const float* __restrict__ in, bf16_t* __restrict__ out, int rows, int cols) {
  __shared__ bf16_t tile[32][33];
  const int r0 = blockIdx.y * 32, c0 = blockIdx.x * 32;
  const int tx = threadIdx.x & 31, ty = threadIdx.x >> 5;  // 32 x 8
#pragma unroll
  for (int i = 0; i < 32; i += 8)
    tile[ty + i][tx] = (__bf16)in[(size_t)(r0 + ty + i) * cols + c0 + tx];
  __syncthreads();
#pragma unroll
  for (int i = 0; i < 32; i += 8)
    out[(size_t)(c0 + ty + i) * rows + r0 + tx] = tile[tx][ty + i];
}

// out[b][c][r] = in[b][r][c], bf16, per-batch via blockIdx.z
__global__ __launch_bounds__(256) void transpose_bf16(
    const bf16_t* __restrict__ in, bf16_t* __restrict__ out, int rows, int cols) {
  __shared__ bf16_t tile[32][33];
  const size_t bo = (size_t)blockIdx.z * rows * cols;
  const int r0 = blockIdx.y * 32, c0 = blockIdx.x * 32;
  const int tx = threadIdx.x & 31, ty = threadIdx.x >> 5;
#pragma unroll
  for (int i = 0; i < 32; i += 8)
    tile[ty + i][tx] = in[bo + (size_t)(r0 + ty + i) * cols + c0 + tx];
  __syncthreads();
#pragma unroll
  for (int i = 0; i < 32; i += 8)
    out[bo + (size_t)(c0 + ty + i) * rows + r0 + tx] = tile[tx][ty + i];
}

// One block (256 thr) per row of n=2048 fp32 scores -> bf16 softmax weights.
__global__ __launch_bounds__(256) void softmax_rows(
    const float* __restrict__ S, bf16_t* __restrict__ W, int n) {
  const int row = blockIdx.x;
  const int t = threadIdx.x;
  const float* p = S + (size_t)row * n;
  bf16_t* wo = W + (size_t)row * n;

  float vals[8];
  float m = -1e30f;
#pragma unroll
  for (int i = 0; i < 8; ++i) {
    vals[i] = p[t + i * 256];
    m = fmaxf(m, vals[i]);
  }
#pragma unroll
  for (int off = 32; off; off >>= 1) m = fmaxf(m, __shfl_xor(m, off));
  __shared__ float redm[4];
  if ((t & 63) == 0) redm[t >> 6] = m;
  __syncthreads();
  m = fmaxf(fmaxf(redm[0], redm[1]), fmaxf(redm[2], redm[3]));

  float s = 0.f;
#pragma unroll
  for (int i = 0; i < 8; ++i) {
    vals[i] = __expf(vals[i] - m);
    s += vals[i];
  }
#pragma unroll
  for (int off = 32; off; off >>= 1) s += __shfl_xor(s, off);
  __shared__ float reds[4];
  if ((t & 63) == 0) reds[t >> 6] = s;
  __syncthreads();
  s = reds[0] + reds[1] + reds[2] + reds[3];
  const float inv = 1.0f / s;
#pragma unroll
  for (int i = 0; i < 8; ++i) wo[t + i * 256] = (__bf16)(vals[i] * inv);
}

extern "C" void kernel_launch(void* const* d_in, const int* in_sizes, int n_in,
                              void* d_out, int out_size, void* d_ws, size_t ws_size,
                              hipStream_t stream) {
  constexpr int Bb = 4, S = 2048, D = 1024;
  constexpr size_t MS = (size_t)Bb * S;  // 8192 total rows

  const float* x  = (const float*)d_in[0];
  const float* Wq = (const float*)d_in[1];
  const float* Wk = (const float*)d_in[2];
  const float* Wv = (const float*)d_in[3];
  float* out = (float*)d_out;

  // Workspace carve (~110 MB total), all 16B-aligned offsets.
  char* p = (char*)d_ws;
  bf16_t* xb  = (bf16_t*)p; p += MS * D * 2;            // x in bf16
  bf16_t* wqt = (bf16_t*)p; p += (size_t)D * D * 2;     // Wq^T bf16 [N,K]
  bf16_t* wkt = (bf16_t*)p; p += (size_t)D * D * 2;
  bf16_t* wvt = (bf16_t*)p; p += (size_t)D * D * 2;
  bf16_t* q   = (bf16_t*)p; p += MS * D * 2;            // [B*S, D]
  bf16_t* k   = (bf16_t*)p; p += MS * D * 2;
  bf16_t* v   = (bf16_t*)p; p += MS * D * 2;
  bf16_t* vt  = (bf16_t*)p; p += MS * D * 2;            // [B][D][S]
  float*  sc  = (float*)p;  p += (size_t)S * S * 4;     // per-batch scores (reused)
  bf16_t* w   = (bf16_t*)p; p += (size_t)S * S * 2;     // per-batch weights (reused)

  cast_f32_to_bf16<<<(MS * D) / 1024, 256, 0, stream>>>(x, xb, (int)(MS * D));
  dim3 gT(D / 32, D / 32);
  cast_transpose<<<gT, 256, 0, stream>>>(Wq, wqt, D, D);
  cast_transpose<<<gT, 256, 0, stream>>>(Wk, wkt, D, D);
  cast_transpose<<<gT, 256, 0, stream>>>(Wv, wvt, D, D);

  dim3 gQKV(D / 128, MS / 128);  // (8, 64)
  gemm_nt<bf16_t><<<gQKV, 256, 0, stream>>>(xb, wqt, q, (int)MS, D, D, 1.0f);
  gemm_nt<bf16_t><<<gQKV, 256, 0, stream>>>(xb, wkt, k, (int)MS, D, D, 1.0f);
  gemm_nt<bf16_t><<<gQKV, 256, 0, stream>>>(xb, wvt, v, (int)MS, D, D, 1.0f);

  transpose_bf16<<<dim3(D / 32, S / 32, Bb), 256, 0, stream>>>(v, vt, S, D);

  const float scl = 1.0f / 32.0f;  // 1/sqrt(D)
  for (int b = 0; b < Bb; ++b) {
    const bf16_t* qb  = q  + (size_t)b * S * D;
    const bf16_t* kb  = k  + (size_t)b * S * D;
    const bf16_t* vtb = vt + (size_t)b * S * D;
    float* ob = out + (size_t)b * S * D;
    // scores = q @ k^T / 32  (k already [N=S, K=D])
    gemm_nt<float><<<dim3(S / 128, S / 128), 256, 0, stream>>>(qb, kb, sc, S, S, D, scl);
    softmax_rows<<<S, 256, 0, stream>>>(sc, w, S);
    // out = w @ v  (vt is [N=D, K=S])
    gemm_nt<float><<<dim3(D / 128, S / 128), 256, 0, stream>>>(w, vtb, ob, S, D, S, 1.0f);
  }
}

// Round 2
// 316.497 us; speedup vs baseline: 1.5848x; 1.5848x over previous
//
#include <hip/hip_runtime.h>
#include <hip/hip_bf16.h>

// SelfAttention: B=4, S=2048, D=1024, fp32 in/out.
// Round 2: batched-over-B attention gemms (blockIdx.z), merged QKV gemm
// (N=3072), all-f16 internal pipeline (better precision than bf16, same
// MFMA rate), in-place f16 softmax. Workspace ~118 MB.
//
// Pipeline:
//   1) cast x -> f16; cast+transpose Wq|Wk|Wv -> f16 Wqkv^T [3D, D]
//   2) gemm_nt: qkv[8192,3072] = x @ Wqkv^T   (1536 blocks)
//   3) transpose v section -> vt [B][D][S]
//   4) scores(f16, in qkv-scale /32) = q k^T   (1024 blocks, batched z)
//   5) in-place row softmax f16->f16           (8192 blocks)
//   6) out(fp32) = w @ vt^T                    (512 blocks, batched z)

typedef _Float16 half_t;
typedef _Float16 half8 __attribute__((ext_vector_type(8)));
typedef _Float16 half4v __attribute__((ext_vector_type(4)));
typedef float f32x4 __attribute__((ext_vector_type(4)));

__device__ __forceinline__ void load16_to_lds(const half_t* g, half_t* l) {
  __builtin_amdgcn_global_load_lds(
      (const __attribute__((address_space(1))) void*)g,
      (__attribute__((address_space(3))) void*)l,
      16, 0, 0);
}

// C[M,N] = scale * (A[M,K] @ B[N,K]^T); A,B f16 K-major with leading dims
// lda/ldb, C row-major OutT with ldc. blockIdx.z selects batch via strides.
// M,N implied by grid (128-multiples); K multiple of 32.
template <typename OutT>
__global__ __launch_bounds__(256) void gemm_nt(
    const half_t* __restrict__ A, const half_t* __restrict__ Bm,
    OutT* __restrict__ C, int lda, int ldb, int ldc,
    long long sA, long long sB, long long sC, int K, float scale) {
  __shared__ __align__(16) half_t As[128 * 32];
  __shared__ __align__(16) half_t Bs[128 * 32];

  A  += (long long)blockIdx.z * sA;
  Bm += (long long)blockIdx.z * sB;
  C  += (long long)blockIdx.z * sC;

  const int t    = threadIdx.x;
  const int m0   = blockIdx.y * 128;
  const int n0   = blockIdx.x * 128;
  const int wave = t >> 6;
  const int lane = t & 63;
  const int wm   = (wave >> 1) * 64;
  const int wn   = (wave & 1) * 64;
  const int lm   = lane & 15;
  const int lq   = lane >> 4;

  // Staging: 128 rows x 32 k per tile = 512 x 16B chunks over 256 threads.
  const int srow = t >> 2;
  const int scc  = (t & 3) * 8;

  const half_t* gA0 = A  + (size_t)(m0 + srow) * lda + scc;
  const half_t* gA1 = gA0 + (size_t)64 * lda;
  const half_t* gB0 = Bm + (size_t)(n0 + srow) * ldb + scc;
  const half_t* gB1 = gB0 + (size_t)64 * ldb;

  half_t* lA0 = &As[t * 8];
  half_t* lA1 = &As[(256 + t) * 8];
  half_t* lB0 = &Bs[t * 8];
  half_t* lB1 = &Bs[(256 + t) * 8];

  f32x4 acc[4][4] = {};

  for (int k0 = 0; k0 < K; k0 += 32) {
    __syncthreads();
    load16_to_lds(gA0 + k0, lA0);
    load16_to_lds(gA1 + k0, lA1);
    load16_to_lds(gB0 + k0, lB0);
    load16_to_lds(gB1 + k0, lB1);
    __syncthreads();

    half8 a[4], b[4];
#pragma unroll
    for (int i = 0; i < 4; ++i)
      a[i] = *(const half8*)&As[(wm + i * 16 + lm) * 32 + lq * 8];
#pragma unroll
    for (int j = 0; j < 4; ++j)
      b[j] = *(const half8*)&Bs[(wn + j * 16 + lm) * 32 + lq * 8];
#pragma unroll
    for (int i = 0; i < 4; ++i)
#pragma unroll
      for (int j = 0; j < 4; ++j)
        acc[i][j] = __builtin_amdgcn_mfma_f32_16x16x32_f16(a[i], b[j], acc[i][j], 0, 0, 0);
  }

  // C/D layout: col = lane&15, row = (lane>>4)*4 + reg  [m89-verified]
#pragma unroll
  for (int i = 0; i < 4; ++i) {
#pragma unroll
    for (int j = 0; j < 4; ++j) {
      const int col = n0 + wn + j * 16 + lm;
#pragma unroll
      for (int r = 0; r < 4; ++r) {
        const int row = m0 + wm + i * 16 + lq * 4 + r;
        C[(size_t)row * ldc + col] = (OutT)(acc[i][j][r] * scale);
      }
    }
  }
}

__global__ __launch_bounds__(256) void cast_f32_to_f16(
    const float* __restrict__ in, half_t* __restrict__ out, int n) {
  int i = (blockIdx.x * 256 + threadIdx.x) * 4;
  if (i >= n) return;
  const float4 v = *reinterpret_cast<const float4*>(in + i);
  half4v o;
  o.x = (half_t)v.x; o.y = (half_t)v.y; o.z = (half_t)v.z; o.w = (half_t)v.w;
  *reinterpret_cast<half4v*>(out + i) = o;
}

// out[c][r] = (f16)in[r][c], in fp32 [rows][cols]
__global__ __launch_bounds__(256) void cast_transpose(
    const float* __restrict__ in, half_t* __restrict__ out, int rows, int cols) {
  __shared__ half_t tile[32][33];
  const int r0 = blockIdx.y * 32, c0 = blockIdx.x * 32;
  const int tx = threadIdx.x & 31, ty = threadIdx.x >> 5;
#pragma unroll
  for (int i = 0; i < 32; i += 8)
    tile[ty + i][tx] = (half_t)in[(size_t)(r0 + ty + i) * cols + c0 + tx];
  __syncthreads();
#pragma unroll
  for (int i = 0; i < 32; i += 8)
    out[(size_t)(c0 + ty + i) * rows + r0 + tx] = tile[tx][ty + i];
}

// out[b][c][r] = in[b][r][c]; in has leading dim ldin, batch strides sIn/sOut.
__global__ __launch_bounds__(256) void transpose_f16(
    const half_t* __restrict__ in, half_t* __restrict__ out,
    int ldin, int rows, long long sIn, long long sOut) {
  __shared__ half_t tile[32][33];
  const half_t* ib = in + (long long)blockIdx.z * sIn;
  half_t* ob = out + (long long)blockIdx.z * sOut;
  const int r0 = blockIdx.y * 32, c0 = blockIdx.x * 32;
  const int tx = threadIdx.x & 31, ty = threadIdx.x >> 5;
#pragma unroll
  for (int i = 0; i < 32; i += 8)
    tile[ty + i][tx] = ib[(size_t)(r0 + ty + i) * ldin + c0 + tx];
  __syncthreads();
#pragma unroll
  for (int i = 0; i < 32; i += 8)
    ob[(size_t)(c0 + ty + i) * rows + r0 + tx] = tile[tx][ty + i];
}

// In-place f16 softmax over rows of n=2048. Grid (S, B); block 256.
// Each block holds its whole row in registers, so in-place is safe.
__global__ __launch_bounds__(256) void softmax_rows(
    half_t* __restrict__ S, int n, long long sBatch) {
  half_t* row = S + (long long)blockIdx.y * sBatch + (size_t)blockIdx.x * n;
  const int t = threadIdx.x;
  half8 hv = *(const half8*)(row + t * 8);

  float vals[8];
  float m = -1e30f;
#pragma unroll
  for (int i = 0; i < 8; ++i) {
    vals[i] = (float)hv[i];
    m = fmaxf(m, vals[i]);
  }
#pragma unroll
  for (int off = 32; off; off >>= 1) m = fmaxf(m, __shfl_xor(m, off));
  __shared__ float redm[4];
  if ((t & 63) == 0) redm[t >> 6] = m;
  __syncthreads();
  m = fmaxf(fmaxf(redm[0], redm[1]), fmaxf(redm[2], redm[3]));

  float s = 0.f;
#pragma unroll
  for (int i = 0; i < 8; ++i) {
    vals[i] = __expf(vals[i] - m);
    s += vals[i];
  }
#pragma unroll
  for (int off = 32; off; off >>= 1) s += __shfl_xor(s, off);
  __shared__ float reds[4];
  if ((t & 63) == 0) reds[t >> 6] = s;
  __syncthreads();
  s = reds[0] + reds[1] + reds[2] + reds[3];
  const float inv = 1.0f / s;

  half8 o;
#pragma unroll
  for (int i = 0; i < 8; ++i) o[i] = (half_t)(vals[i] * inv);
  *(half8*)(row + t * 8) = o;
}

extern "C" void kernel_launch(void* const* d_in, const int* in_sizes, int n_in,
                              void* d_out, int out_size, void* d_ws, size_t ws_size,
                              hipStream_t stream) {
  constexpr int Bb = 4, S = 2048, D = 1024;
  constexpr int N3 = 3 * D;              // 3072
  constexpr size_t MS = (size_t)Bb * S;  // 8192 rows

  const float* x  = (const float*)d_in[0];
  const float* Wq = (const float*)d_in[1];
  const float* Wk = (const float*)d_in[2];
  const float* Wv = (const float*)d_in[3];
  float* out = (float*)d_out;

  // Workspace carve (~118 MB).
  char* p = (char*)d_ws;
  half_t* xh  = (half_t*)p; p += MS * D * 2;                 // 16 MB
  half_t* wt  = (half_t*)p; p += (size_t)N3 * D * 2;         // 6 MB, Wqkv^T [3D, D]
  half_t* qkv = (half_t*)p; p += MS * (size_t)N3 * 2;        // 48 MB, [B*S, 3D]
  half_t* vt  = (half_t*)p; p += MS * D * 2;                 // 16 MB, [B][D][S]
  half_t* sc  = (half_t*)p; p += (size_t)Bb * S * S * 2;     // 32 MB, scores/weights

  cast_f32_to_f16<<<(MS * D) / 1024, 256, 0, stream>>>(x, xh, (int)(MS * D));
  dim3 gT(D / 32, D / 32);
  cast_transpose<<<gT, 256, 0, stream>>>(Wq, wt + 0 * (size_t)D * D, D, D);
  cast_transpose<<<gT, 256, 0, stream>>>(Wk, wt + 1 * (size_t)D * D, D, D);
  cast_transpose<<<gT, 256, 0, stream>>>(Wv, wt + 2 * (size_t)D * D, D, D);

  // qkv = x @ Wqkv^T : M=8192, N=3072, K=1024 (1536 blocks)
  gemm_nt<half_t><<<dim3(N3 / 128, MS / 128), 256, 0, stream>>>(
      xh, wt, qkv, D, D, N3, 0, 0, 0, D, 1.0f);

  // vt[b][d][s] = v[b][s][d]; v is qkv section at col offset 2D, ld = 3072
  transpose_f16<<<dim3(D / 32, S / 32, Bb), 256, 0, stream>>>(
      qkv + 2 * D, vt, N3, S, (long long)S * N3, (long long)D * S);

  // scores = q k^T / 32, f16, batched over z (1024 blocks)
  gemm_nt<half_t><<<dim3(S / 128, S / 128, Bb), 256, 0, stream>>>(
      qkv + 0 * D, qkv + 1 * D, sc, N3, N3, S,
      (long long)S * N3, (long long)S * N3, (long long)S * S, D, 1.0f / 32.0f);

  // in-place softmax
  softmax_rows<<<dim3(S, Bb), 256, 0, stream>>>(sc, S, (long long)S * S);

  // out = w @ v  (vt is [D, S] K-major), batched over z (512 blocks)
  gemm_nt<float><<<dim3(D / 128, S / 128, Bb), 256, 0, stream>>>(
      sc, vt, out, S, S, D,
      (long long)S * S, (long long)D * S, (long long)S * D, S, 1.0f);
}

// Round 3
// 274.984 us; speedup vs baseline: 1.8240x; 1.1510x over previous
//
#include <hip/hip_runtime.h>
#include <hip/hip_bf16.h>

// SelfAttention: B=4, S=2048, D=1024, fp32 in/out.
// Round 3: gemm_nt reworked: BK=64 (half the barrier drains), XOR-swizzled
// LDS chunk layout (kills ds_read_b128 bank conflicts: each quarter-wave
// spreads over 8 banks 2-way instead of 2 banks 8-way).
// Pipeline unchanged from R2 (all-f16 internal, batched z-gemms):
//   1) cast x -> f16; cast+transpose Wq|Wk|Wv -> f16 Wqkv^T [3D, D]
//   2) gemm_nt: qkv[8192,3072] = x @ Wqkv^T   (1536 blocks)
//   3) transpose v section -> vt [B][D][S]
//   4) scores(f16, /32) = q k^T                (1024 blocks, batched z)
//   5) in-place row softmax f16                (8192 blocks)
//   6) out(fp32) = w @ vt^T                    (512 blocks, batched z)

typedef _Float16 half_t;
typedef _Float16 half8 __attribute__((ext_vector_type(8)));
typedef _Float16 half4v __attribute__((ext_vector_type(4)));
typedef float f32x4 __attribute__((ext_vector_type(4)));

__device__ __forceinline__ void load16_to_lds(const half_t* g, half_t* l) {
  __builtin_amdgcn_global_load_lds(
      (const __attribute__((address_space(1))) void*)g,
      (__attribute__((address_space(3))) void*)l,
      16, 0, 0);
}

// C[M,N] = scale * (A[M,K] @ B[N,K]^T); A,B f16 K-major with leading dims
// lda/ldb, C row-major OutT with ldc. blockIdx.z selects batch via strides.
// K multiple of 64. Tile 128x128, BK=64.
//
// LDS layout (per matrix, 128 rows x 8 chunks of 16B):
//   LDS[row r][pos p] holds global k-chunk (p ^ (r&7)) of row r.
// Staged as: thread t, instr n -> LDS chunk idx (n*256+t) -> r=n*32+(t>>3),
// p=t&7, so thread t loads global chunk (t&7)^((t>>3)&7) of row n*32+(t>>3).
// Readers XOR the same: row R, logical chunk c -> pos c^(R&7).
// Bank math for a quarter-wave (fixed lq, R=wm+i*16+lm, lm=0..15):
//   byte = R*128 + ((kk*4+lq)^(lm&7))*16 -> bank = 4*((kk*4+lq)^(lm&7))
//   -> 8 banks x 2-way = conflict-free (2-way is free on gfx950).
template <typename OutT>
__global__ __launch_bounds__(256) void gemm_nt(
    const half_t* __restrict__ A, const half_t* __restrict__ Bm,
    OutT* __restrict__ C, int lda, int ldb, int ldc,
    long long sA, long long sB, long long sC, int K, float scale) {
  __shared__ __align__(16) half_t As[128 * 64];
  __shared__ __align__(16) half_t Bs[128 * 64];

  A  += (long long)blockIdx.z * sA;
  Bm += (long long)blockIdx.z * sB;
  C  += (long long)blockIdx.z * sC;

  const int t    = threadIdx.x;
  const int m0   = blockIdx.y * 128;
  const int n0   = blockIdx.x * 128;
  const int wave = t >> 6;
  const int lane = t & 63;
  const int wm   = (wave >> 1) * 64;
  const int wn   = (wave & 1) * 64;
  const int lm   = lane & 15;
  const int lq   = lane >> 4;
  const int lswz = lm & 7;  // read-side XOR key (R&7 == lm&7 for all subtiles)

  // Staging addresses
  const int trow = t >> 3;                       // 0..31
  const int tchk = (t & 7) ^ (trow & 7);         // swizzled global k-chunk

  const half_t* gA0 = A  + (size_t)(m0 + trow) * lda + tchk * 8;
  const half_t* gB0 = Bm + (size_t)(n0 + trow) * ldb + tchk * 8;
  const size_t stepA = (size_t)32 * lda;
  const size_t stepB = (size_t)32 * ldb;

  half_t* lA0 = &As[t * 8];
  half_t* lB0 = &Bs[t * 8];

  f32x4 acc[4][4] = {};

  for (int k0 = 0; k0 < K; k0 += 64) {
    __syncthreads();  // previous iter's LDS reads complete
#pragma unroll
    for (int n = 0; n < 4; ++n) {
      load16_to_lds(gA0 + n * stepA + k0, lA0 + n * 2048);
      load16_to_lds(gB0 + n * stepB + k0, lB0 + n * 2048);
    }
    __syncthreads();  // staging drained

    for (int kk = 0; kk < 2; ++kk) {
      const int pos = ((kk * 4 + lq) ^ lswz) * 8;
      half8 a[4], b[4];
#pragma unroll
      for (int i = 0; i < 4; ++i)
        a[i] = *(const half8*)&As[(wm + i * 16 + lm) * 64 + pos];
#pragma unroll
      for (int j = 0; j < 4; ++j)
        b[j] = *(const half8*)&Bs[(wn + j * 16 + lm) * 64 + pos];
#pragma unroll
      for (int i = 0; i < 4; ++i)
#pragma unroll
        for (int j = 0; j < 4; ++j)
          acc[i][j] = __builtin_amdgcn_mfma_f32_16x16x32_f16(a[i], b[j], acc[i][j], 0, 0, 0);
    }
  }

  // C/D layout: col = lane&15, row = (lane>>4)*4 + reg  [m89-verified]
#pragma unroll
  for (int i = 0; i < 4; ++i) {
#pragma unroll
    for (int j = 0; j < 4; ++j) {
      const int col = n0 + wn + j * 16 + lm;
#pragma unroll
      for (int r = 0; r < 4; ++r) {
        const int row = m0 + wm + i * 16 + lq * 4 + r;
        C[(size_t)row * ldc + col] = (OutT)(acc[i][j][r] * scale);
      }
    }
  }
}

__global__ __launch_bounds__(256) void cast_f32_to_f16(
    const float* __restrict__ in, half_t* __restrict__ out, int n) {
  int i = (blockIdx.x * 256 + threadIdx.x) * 4;
  if (i >= n) return;
  const float4 v = *reinterpret_cast<const float4*>(in + i);
  half4v o;
  o.x = (half_t)v.x; o.y = (half_t)v.y; o.z = (half_t)v.z; o.w = (half_t)v.w;
  *reinterpret_cast<half4v*>(out + i) = o;
}

// out[c][r] = (f16)in[r][c], in fp32 [rows][cols]
__global__ __launch_bounds__(256) void cast_transpose(
    const float* __restrict__ in, half_t* __restrict__ out, int rows, int cols) {
  __shared__ half_t tile[32][33];
  const int r0 = blockIdx.y * 32, c0 = blockIdx.x * 32;
  const int tx = threadIdx.x & 31, ty = threadIdx.x >> 5;
#pragma unroll
  for (int i = 0; i < 32; i += 8)
    tile[ty + i][tx] = (half_t)in[(size_t)(r0 + ty + i) * cols + c0 + tx];
  __syncthreads();
#pragma unroll
  for (int i = 0; i < 32; i += 8)
    out[(size_t)(c0 + ty + i) * rows + r0 + tx] = tile[tx][ty + i];
}

// out[b][c][r] = in[b][r][c]; in has leading dim ldin, batch strides sIn/sOut.
__global__ __launch_bounds__(256) void transpose_f16(
    const half_t* __restrict__ in, half_t* __restrict__ out,
    int ldin, int rows, long long sIn, long long sOut) {
  __shared__ half_t tile[32][33];
  const half_t* ib = in + (long long)blockIdx.z * sIn;
  half_t* ob = out + (long long)blockIdx.z * sOut;
  const int r0 = blockIdx.y * 32, c0 = blockIdx.x * 32;
  const int tx = threadIdx.x & 31, ty = threadIdx.x >> 5;
#pragma unroll
  for (int i = 0; i < 32; i += 8)
    tile[ty + i][tx] = ib[(size_t)(r0 + ty + i) * ldin + c0 + tx];
  __syncthreads();
#pragma unroll
  for (int i = 0; i < 32; i += 8)
    ob[(size_t)(c0 + ty + i) * rows + r0 + tx] = tile[tx][ty + i];
}

// In-place f16 softmax over rows of n=2048. Grid (S, B); block 256.
__global__ __launch_bounds__(256) void softmax_rows(
    half_t* __restrict__ S, int n, long long sBatch) {
  half_t* row = S + (long long)blockIdx.y * sBatch + (size_t)blockIdx.x * n;
  const int t = threadIdx.x;
  half8 hv = *(const half8*)(row + t * 8);

  float vals[8];
  float m = -1e30f;
#pragma unroll
  for (int i = 0; i < 8; ++i) {
    vals[i] = (float)hv[i];
    m = fmaxf(m, vals[i]);
  }
#pragma unroll
  for (int off = 32; off; off >>= 1) m = fmaxf(m, __shfl_xor(m, off));
  __shared__ float redm[4];
  if ((t & 63) == 0) redm[t >> 6] = m;
  __syncthreads();
  m = fmaxf(fmaxf(redm[0], redm[1]), fmaxf(redm[2], redm[3]));

  float s = 0.f;
#pragma unroll
  for (int i = 0; i < 8; ++i) {
    vals[i] = __expf(vals[i] - m);
    s += vals[i];
  }
#pragma unroll
  for (int off = 32; off; off >>= 1) s += __shfl_xor(s, off);
  __shared__ float reds[4];
  if ((t & 63) == 0) reds[t >> 6] = s;
  __syncthreads();
  s = reds[0] + reds[1] + reds[2] + reds[3];
  const float inv = 1.0f / s;

  half8 o;
#pragma unroll
  for (int i = 0; i < 8; ++i) o[i] = (half_t)(vals[i] * inv);
  *(half8*)(row + t * 8) = o;
}

extern "C" void kernel_launch(void* const* d_in, const int* in_sizes, int n_in,
                              void* d_out, int out_size, void* d_ws, size_t ws_size,
                              hipStream_t stream) {
  constexpr int Bb = 4, S = 2048, D = 1024;
  constexpr int N3 = 3 * D;              // 3072
  constexpr size_t MS = (size_t)Bb * S;  // 8192 rows

  const float* x  = (const float*)d_in[0];
  const float* Wq = (const float*)d_in[1];
  const float* Wk = (const float*)d_in[2];
  const float* Wv = (const float*)d_in[3];
  float* out = (float*)d_out;

  // Workspace carve (~118 MB).
  char* p = (char*)d_ws;
  half_t* xh  = (half_t*)p; p += MS * D * 2;                 // 16 MB
  half_t* wt  = (half_t*)p; p += (size_t)N3 * D * 2;         // 6 MB, Wqkv^T [3D, D]
  half_t* qkv = (half_t*)p; p += MS * (size_t)N3 * 2;        // 48 MB, [B*S, 3D]
  half_t* vt  = (half_t*)p; p += MS * D * 2;                 // 16 MB, [B][D][S]
  half_t* sc  = (half_t*)p; p += (size_t)Bb * S * S * 2;     // 32 MB, scores/weights

  cast_f32_to_f16<<<(MS * D) / 1024, 256, 0, stream>>>(x, xh, (int)(MS * D));
  dim3 gT(D / 32, D / 32);
  cast_transpose<<<gT, 256, 0, stream>>>(Wq, wt + 0 * (size_t)D * D, D, D);
  cast_transpose<<<gT, 256, 0, stream>>>(Wk, wt + 1 * (size_t)D * D, D, D);
  cast_transpose<<<gT, 256, 0, stream>>>(Wv, wt + 2 * (size_t)D * D, D, D);

  // qkv = x @ Wqkv^T : M=8192, N=3072, K=1024 (1536 blocks)
  gemm_nt<half_t><<<dim3(N3 / 128, MS / 128), 256, 0, stream>>>(
      xh, wt, qkv, D, D, N3, 0, 0, 0, D, 1.0f);

  // vt[b][d][s] = v[b][s][d]; v is qkv section at col offset 2D, ld = 3072
  transpose_f16<<<dim3(D / 32, S / 32, Bb), 256, 0, stream>>>(
      qkv + 2 * D, vt, N3, S, (long long)S * N3, (long long)D * S);

  // scores = q k^T / 32, f16, batched over z (1024 blocks)
  gemm_nt<half_t><<<dim3(S / 128, S / 128, Bb), 256, 0, stream>>>(
      qkv + 0 * D, qkv + 1 * D, sc, N3, N3, S,
      (long long)S * N3, (long long)S * N3, (long long)S * S, D, 1.0f / 32.0f);

  // in-place softmax
  softmax_rows<<<dim3(S, Bb), 256, 0, stream>>>(sc, S, (long long)S * S);

  // out = w @ v  (vt is [D, S] K-major), batched over z (512 blocks)
  gemm_nt<float><<<dim3(D / 128, S / 128, Bb), 256, 0, stream>>>(
      sc, vt, out, S, S, D,
      (long long)S * S, (long long)D * S, (long long)S * D, S, 1.0f);
}